// Round 1
// baseline (256.575 us; speedup 1.0000x reference)
//
#include <hip/hip_runtime.h>

// Patch_Embed_Rotate: per-16x16-patch conditional transpose.
// out[b,c,hi*16+i,wi*16+j] = mask[b,wi,hi] ? x[b,c,hi*16+j,wi*16+i]
//                                          : x[b,c,hi*16+i,wi*16+j]
// B=256, C=3, H=W=224, P=16 -> 14x14 patches, 150528 channel-patches.
// Pure data movement: ~308 MB total traffic -> HBM-bound, ~49 us floor.

#define IMG_W 224
#define IMG_HW 50176      // 224*224
#define NPATCH 14

__global__ __launch_bounds__(256) void patch_rotate_kernel(
    const float* __restrict__ x,
    const int*   __restrict__ mask,
    float*       __restrict__ out)
{
    // One wave (64 lanes) per channel-patch. lane = r*4 + q:
    //   r in [0,16) = patch row, q in [0,4) = float4 column group.
    // LDS tile padded to 20 floats/row: transposed scalar reads are
    // at worst 2-way bank conflicted (free on gfx950, m136).
    __shared__ float lds[4][16][20];

    const int wv   = threadIdx.x >> 6;
    const int lane = threadIdx.x & 63;
    const int r    = lane >> 2;
    const int q    = lane & 3;

    // channel-patch index -> (b, c, hi, wi). Layout chosen so adjacent
    // waves touch adjacent wi (contiguous 64B lines along W) for L2 locality.
    const int p  = blockIdx.x * 4 + wv;
    const int wi = p % NPATCH;
    int t        = p / NPATCH;
    const int hi = t % NPATCH;
    t            = t / NPATCH;
    const int c  = t % 3;
    const int b  = t / 3;

    const int base = (b * 3 + c) * IMG_HW + hi * (16 * IMG_W) + wi * 16;

    // Coalesced float4 load of input row r, cols [4q, 4q+4).
    const float4 v = *(const float4*)(x + base + r * IMG_W + 4 * q);

    // Stage into LDS (always — keeps __syncthreads() uniform across waves
    // regardless of each wave's mask value).
    *(float4*)&lds[wv][r][4 * q] = v;
    __syncthreads();

    // mask[b, wi, hi] — W-patch index is the SECOND dim of the mask.
    // One address per wave -> broadcast load.
    const int m = mask[(b * NPATCH + wi) * NPATCH + hi];

    float4 res;
    if (m) {
        // out row r, cols 4q+k  =  in rows 4q+k, col r  (patch transpose)
        res.x = lds[wv][4 * q + 0][r];
        res.y = lds[wv][4 * q + 1][r];
        res.z = lds[wv][4 * q + 2][r];
        res.w = lds[wv][4 * q + 3][r];
    } else {
        res = v;
    }

    // Coalesced float4 store to the same patch location.
    *(float4*)(out + base + r * IMG_W + 4 * q) = res;
}

extern "C" void kernel_launch(void* const* d_in, const int* in_sizes, int n_in,
                              void* d_out, int out_size, void* d_ws, size_t ws_size,
                              hipStream_t stream) {
    const float* x    = (const float*)d_in[0];
    const int*   mask = (const int*)d_in[1];
    float*       out  = (float*)d_out;

    // in_sizes[0] = 256*3*224*224 = 38535168 elems -> 150528 channel-patches
    const int n_cpatch = in_sizes[0] / 256;
    const int blocks   = n_cpatch / 4;   // 4 waves/block, exact division (37632)

    patch_rotate_kernel<<<blocks, 256, 0, stream>>>(x, mask, out);
}